// Round 2
// baseline (447.178 us; speedup 1.0000x reference)
//
#include <hip/hip_runtime.h>
#include <stdint.h>

#define N 4096
#define BM 128
#define BN 128
#define BK 32

typedef short bf16x8 __attribute__((ext_vector_type(8)));
typedef float f32x4 __attribute__((ext_vector_type(4)));

__device__ __forceinline__ unsigned short f2bf(float x) {
  union { float f; unsigned int u; } v; v.f = x;
  unsigned int u = v.u;
  unsigned int r = (u + 0x7fffu + ((u >> 16) & 1u)) >> 16;  // RNE
  return (unsigned short)r;
}

__device__ __forceinline__ void gload16(const unsigned short* g, unsigned short* l) {
  __builtin_amdgcn_global_load_lds(
      (const __attribute__((address_space(1))) unsigned int*)g,
      (__attribute__((address_space(3))) unsigned int*)l, 16, 0, 0);
}

// ---- K1: W2 fp32 -> bf16 scratch, fused c = b1 @ W2^T + b2 ----
__global__ __launch_bounds__(256) void convert_w2(const float* __restrict__ W2,
                                                  const float* __restrict__ b1,
                                                  const float* __restrict__ b2,
                                                  unsigned short* __restrict__ W2b,
                                                  float* __restrict__ c) {
  const int i = blockIdx.x;
  const int t = threadIdx.x;
  const float* row = W2 + (size_t)i * N;
  unsigned short* orow = W2b + (size_t)i * N;
  float dot = 0.f;
#pragma unroll
  for (int q = 0; q < 4; ++q) {
    int idx = (q * 256 + t) * 4;
    float4 w = *(const float4*)(row + idx);
    float4 b = *(const float4*)(b1 + idx);
    dot += w.x * b.x + w.y * b.y + w.z * b.z + w.w * b.w;
    ushort4 o;
    o.x = f2bf(w.x); o.y = f2bf(w.y); o.z = f2bf(w.z); o.w = f2bf(w.w);
    *(ushort4*)(orow + idx) = o;
  }
  __shared__ float red[256];
  red[t] = dot;
  __syncthreads();
  for (int s = 128; s > 0; s >>= 1) {
    if (t < s) red[t] += red[t + s];
    __syncthreads();
  }
  if (t == 0) c[i] = red[0] + b2[i];
}

// ---- K2: W1 fp32 [k][j] -> bf16 W1T [j][k] (LDS tile transpose) ----
__global__ __launch_bounds__(256) void transpose_w1(const float* __restrict__ W1,
                                                    unsigned short* __restrict__ W1T) {
  __shared__ float tile[64 * 65];
  const int t = threadIdx.x;
  const int j0 = blockIdx.x * 64, k0 = blockIdx.y * 64;
#pragma unroll
  for (int s = 0; s < 4; ++s) {
    int ck = s * 256 + t;          // 0..1023
    int row = ck >> 4;             // k_local 0..63
    int col = (ck & 15) * 4;       // j_local
    float4 v = *(const float4*)(W1 + (size_t)(k0 + row) * N + j0 + col);
    float* d = &tile[row * 65 + col];
    d[0] = v.x; d[1] = v.y; d[2] = v.z; d[3] = v.w;
  }
  __syncthreads();
  int jl = t >> 2, ch = (t & 3) * 16;
  alignas(16) unsigned short outv[16];
#pragma unroll
  for (int m = 0; m < 16; ++m) outv[m] = f2bf(tile[(ch + m) * 65 + jl]);
  uint4* dst = (uint4*)(W1T + (size_t)(j0 + jl) * N + k0 + ch);
  dst[0] = *(const uint4*)&outv[0];
  dst[1] = *(const uint4*)&outv[8];
}

// ---- K3: S = W2b @ W1Tb^T (bf16 MFMA), fused sign-selected bound reductions ----
__global__ __launch_bounds__(256) void gemm_bounds(const unsigned short* __restrict__ A,  // W2b [i][k]
                                                   const unsigned short* __restrict__ B,  // W1Tb [j][k]
                                                   const float* __restrict__ lb0,
                                                   const float* __restrict__ ub0,
                                                   float* __restrict__ lb_acc,
                                                   float* __restrict__ ub_acc) {
  __shared__ unsigned short As[BM * BK];
  __shared__ unsigned short Bs[BN * BK];
  const int t = threadIdx.x;
  const int lane = t & 63, w = t >> 6;
  const int wm = (w >> 1) * 64, wn = (w & 1) * 64;
  const int i0 = blockIdx.y * BM, j0 = blockIdx.x * BN;
  const int quad = lane >> 4, l16 = lane & 15;

  f32x4 acc[4][4] = {};

  // staging pointers: chunk t covers (row=t>>2, 16B piece t&3); chunk t+256 is +64 rows
  const unsigned short* ga = A + (size_t)(i0 + (t >> 2)) * N + (t & 3) * 8;
  const unsigned short* gb = B + (size_t)(j0 + (t >> 2)) * N + (t & 3) * 8;
  unsigned short* lA0 = &As[t * 8];
  unsigned short* lA1 = &As[(t + 256) * 8];
  unsigned short* lB0 = &Bs[t * 8];
  unsigned short* lB1 = &Bs[(t + 256) * 8];

  for (int kt = 0; kt < N / BK; ++kt) {
    __syncthreads();
    gload16(ga, lA0);
    gload16(ga + (size_t)64 * N, lA1);
    gload16(gb, lB0);
    gload16(gb + (size_t)64 * N, lB1);
    __syncthreads();
    bf16x8 af[4], bfr[4];
#pragma unroll
    for (int tm = 0; tm < 4; ++tm)
      af[tm] = *(const bf16x8*)&As[(wm + tm * 16 + l16) * BK + quad * 8];
#pragma unroll
    for (int tn = 0; tn < 4; ++tn)
      bfr[tn] = *(const bf16x8*)&Bs[(wn + tn * 16 + l16) * BK + quad * 8];
#pragma unroll
    for (int tm = 0; tm < 4; ++tm)
#pragma unroll
      for (int tn = 0; tn < 4; ++tn)
        acc[tm][tn] = __builtin_amdgcn_mfma_f32_16x16x32_bf16(af[tm], bfr[tn], acc[tm][tn], 0, 0, 0);
    ga += BK;
    gb += BK;
  }

  // epilogue: lbounds_i += (s>0?lb0_j:ub0_j)*s ; ubounds_i += (s>0?ub0_j:lb0_j)*s
  float lbv[4], ubv[4];
#pragma unroll
  for (int tn = 0; tn < 4; ++tn) {
    int j = j0 + wn + tn * 16 + l16;
    lbv[tn] = lb0[j];
    ubv[tn] = ub0[j];
  }
#pragma unroll
  for (int tm = 0; tm < 4; ++tm) {
#pragma unroll
    for (int r = 0; r < 4; ++r) {
      float ls = 0.f, us = 0.f;
#pragma unroll
      for (int tn = 0; tn < 4; ++tn) {
        float s = acc[tm][tn][r];
        ls += s * (s > 0.f ? lbv[tn] : ubv[tn]);
        us += s * (s > 0.f ? ubv[tn] : lbv[tn]);
      }
#pragma unroll
      for (int off = 1; off < 16; off <<= 1) {
        ls += __shfl_xor(ls, off, 64);
        us += __shfl_xor(us, off, 64);
      }
      if (l16 == 0) {
        int i = i0 + wm + tm * 16 + quad * 4 + r;
        atomicAdd(&lb_acc[i], ls);
        atomicAdd(&ub_acc[i], us);
      }
    }
  }
}

// ---- K4: DeepPolyReLU elementwise + diagonal patch ----
__global__ __launch_bounds__(256) void epilogue_k(const float* __restrict__ cvec,
                                                  const float* __restrict__ lb_acc,
                                                  const float* __restrict__ ub_acc,
                                                  const float* __restrict__ raw_alpha,
                                                  float* __restrict__ out) {
  int i = blockIdx.x * 256 + threadIdx.x;
  if (i >= N) return;
  float cc = cvec[i];
  float lb = lb_acc[i] + cc;
  float ub = ub_acc[i] + cc;
  float alpha = 1.f / (1.f + expf(-raw_alpha[i]));
  float denom = ub - lb;
  float slope = (denom == 0.f) ? 0.f : ub / denom;
  bool below = ub <= 0.f, above = lb >= 0.f;
  bool crossing = !(below || above);
  float base = above ? 1.f : 0.f;
  float uslope = crossing ? slope : base;
  float uinter = crossing ? (1.f - slope) * ub : 0.f;
  float l1 = crossing ? 0.f : base;
  float l2 = crossing ? 1.f : base;
  float lslope = alpha * l1 + (1.f - alpha) * l2;
  size_t NN = (size_t)N * N;
  out[(size_t)i * N + i] = lslope;                 // diag(lslope)
  // lintercept at [NN, NN+N) stays zero from memset
  out[NN + N + (size_t)i * N + i] = uslope;        // diag(uslope)
  out[2 * NN + N + i] = uinter;                    // uintercept
}

extern "C" void kernel_launch(void* const* d_in, const int* in_sizes, int n_in,
                              void* d_out, int out_size, void* d_ws, size_t ws_size,
                              hipStream_t stream) {
  const float* raw_alpha = (const float*)d_in[0];
  const float* lb0 = (const float*)d_in[1];
  const float* ub0 = (const float*)d_in[2];
  const float* W1 = (const float*)d_in[3];
  const float* b1 = (const float*)d_in[4];
  const float* W2 = (const float*)d_in[5];
  const float* b2 = (const float*)d_in[6];

  float* cvec = (float*)d_ws;        // [N]
  float* lb_acc = cvec + N;          // [N]
  float* ub_acc = cvec + 2 * N;      // [N]

  // d_out (134 MB) doubles as bf16 scratch until the final memset
  unsigned short* W2b = (unsigned short*)d_out;       // [N*N] bf16, 32 MB
  unsigned short* W1Tb = W2b + (size_t)N * N;         // [N*N] bf16, 32 MB

  (void)hipMemsetAsync(d_ws, 0, 3 * N * sizeof(float), stream);
  convert_w2<<<N, 256, 0, stream>>>(W2, b1, b2, W2b, cvec);
  transpose_w1<<<dim3(N / 64, N / 64), 256, 0, stream>>>(W1, W1Tb);
  gemm_bounds<<<dim3(N / BN, N / BM), 256, 0, stream>>>(W2b, W1Tb, lb0, ub0, lb_acc, ub_acc);
  (void)hipMemsetAsync(d_out, 0, (size_t)out_size * sizeof(float), stream);
  epilogue_k<<<(N + 255) / 256, 256, 0, stream>>>(cvec, lb_acc, ub_acc, raw_alpha, (float*)d_out);
}

// Round 3
// 411.866 us; speedup vs baseline: 1.0857x; 1.0857x over previous
//
#include <hip/hip_runtime.h>
#include <stdint.h>

#define N 4096
#define BM 128
#define BN 128
#define BK 32

typedef short bf16x8 __attribute__((ext_vector_type(8)));
typedef float f32x4 __attribute__((ext_vector_type(4)));

__device__ __forceinline__ unsigned short f2bf(float x) {
  union { float f; unsigned int u; } v; v.f = x;
  unsigned int u = v.u;
  unsigned int r = (u + 0x7fffu + ((u >> 16) & 1u)) >> 16;  // RNE
  return (unsigned short)r;
}

__device__ __forceinline__ void gload16(const unsigned short* g, unsigned short* l) {
  __builtin_amdgcn_global_load_lds(
      (const __attribute__((address_space(1))) unsigned int*)g,
      (__attribute__((address_space(3))) unsigned int*)l, 16, 0, 0);
}

// ---- K1: W2 fp32 -> bf16 scratch, fused c = b1 @ W2^T + b2 ----
__global__ __launch_bounds__(256) void convert_w2(const float* __restrict__ W2,
                                                  const float* __restrict__ b1,
                                                  const float* __restrict__ b2,
                                                  unsigned short* __restrict__ W2b,
                                                  float* __restrict__ c) {
  const int i = blockIdx.x;
  const int t = threadIdx.x;
  const float* row = W2 + (size_t)i * N;
  unsigned short* orow = W2b + (size_t)i * N;
  float dot = 0.f;
#pragma unroll
  for (int q = 0; q < 4; ++q) {
    int idx = (q * 256 + t) * 4;
    float4 w = *(const float4*)(row + idx);
    float4 b = *(const float4*)(b1 + idx);
    dot += w.x * b.x + w.y * b.y + w.z * b.z + w.w * b.w;
    ushort4 o;
    o.x = f2bf(w.x); o.y = f2bf(w.y); o.z = f2bf(w.z); o.w = f2bf(w.w);
    *(ushort4*)(orow + idx) = o;
  }
  __shared__ float red[256];
  red[t] = dot;
  __syncthreads();
  for (int s = 128; s > 0; s >>= 1) {
    if (t < s) red[t] += red[t + s];
    __syncthreads();
  }
  if (t == 0) c[i] = red[0] + b2[i];
}

// ---- K2: W1 fp32 [k][j] -> bf16 W1T [j][k] (LDS tile transpose) ----
__global__ __launch_bounds__(256) void transpose_w1(const float* __restrict__ W1,
                                                    unsigned short* __restrict__ W1T) {
  __shared__ float tile[64 * 65];
  const int t = threadIdx.x;
  const int j0 = blockIdx.x * 64, k0 = blockIdx.y * 64;
#pragma unroll
  for (int s = 0; s < 4; ++s) {
    int ck = s * 256 + t;          // 0..1023
    int row = ck >> 4;             // k_local 0..63
    int col = (ck & 15) * 4;       // j_local
    float4 v = *(const float4*)(W1 + (size_t)(k0 + row) * N + j0 + col);
    float* d = &tile[row * 65 + col];
    d[0] = v.x; d[1] = v.y; d[2] = v.z; d[3] = v.w;
  }
  __syncthreads();
  int jl = t >> 2, ch = (t & 3) * 16;
  alignas(16) unsigned short outv[16];
#pragma unroll
  for (int m = 0; m < 16; ++m) outv[m] = f2bf(tile[(ch + m) * 65 + jl]);
  uint4* dst = (uint4*)(W1T + (size_t)(j0 + jl) * N + k0 + ch);
  dst[0] = *(const uint4*)&outv[0];
  dst[1] = *(const uint4*)&outv[8];
}

// ---- K3: S = W2b @ W1Tb^T (bf16 MFMA), fused sign-selected bound reductions ----
__global__ __launch_bounds__(256, 4) void gemm_bounds(const unsigned short* __restrict__ A,  // W2b [i][k]
                                                      const unsigned short* __restrict__ B,  // W1Tb [j][k]
                                                      const float* __restrict__ lb0,
                                                      const float* __restrict__ ub0,
                                                      float* __restrict__ lb_acc,
                                                      float* __restrict__ ub_acc) {
  __shared__ unsigned short As[BM * BK];
  __shared__ unsigned short Bs[BN * BK];
  const int t = threadIdx.x;
  const int lane = t & 63, w = t >> 6;
  const int wm = (w >> 1) * 64, wn = (w & 1) * 64;
  const int i0 = blockIdx.y * BM, j0 = blockIdx.x * BN;
  const int quad = lane >> 4, l16 = lane & 15;

  f32x4 acc[4][4] = {};

  // staging pointers: chunk t covers (row=t>>2, 16B piece t&3); chunk t+256 is +64 rows
  const unsigned short* ga = A + (size_t)(i0 + (t >> 2)) * N + (t & 3) * 8;
  const unsigned short* gb = B + (size_t)(j0 + (t >> 2)) * N + (t & 3) * 8;
  unsigned short* lA0 = &As[t * 8];
  unsigned short* lA1 = &As[(t + 256) * 8];
  unsigned short* lB0 = &Bs[t * 8];
  unsigned short* lB1 = &Bs[(t + 256) * 8];

  for (int kt = 0; kt < N / BK; ++kt) {
    __syncthreads();
    gload16(ga, lA0);
    gload16(ga + (size_t)64 * N, lA1);
    gload16(gb, lB0);
    gload16(gb + (size_t)64 * N, lB1);
    __syncthreads();
    bf16x8 af[4], bfr[4];
#pragma unroll
    for (int tm = 0; tm < 4; ++tm)
      af[tm] = *(const bf16x8*)&As[(wm + tm * 16 + l16) * BK + quad * 8];
#pragma unroll
    for (int tn = 0; tn < 4; ++tn)
      bfr[tn] = *(const bf16x8*)&Bs[(wn + tn * 16 + l16) * BK + quad * 8];
#pragma unroll
    for (int tm = 0; tm < 4; ++tm)
#pragma unroll
      for (int tn = 0; tn < 4; ++tn)
        acc[tm][tn] = __builtin_amdgcn_mfma_f32_16x16x32_bf16(af[tm], bfr[tn], acc[tm][tn], 0, 0, 0);
    ga += BK;
    gb += BK;
  }

  // epilogue: lbounds_i += (s>0?lb0_j:ub0_j)*s ; ubounds_i += (s>0?ub0_j:lb0_j)*s
  float lbv[4], ubv[4];
#pragma unroll
  for (int tn = 0; tn < 4; ++tn) {
    int j = j0 + wn + tn * 16 + l16;
    lbv[tn] = lb0[j];
    ubv[tn] = ub0[j];
  }
#pragma unroll
  for (int tm = 0; tm < 4; ++tm) {
#pragma unroll
    for (int r = 0; r < 4; ++r) {
      float ls = 0.f, us = 0.f;
#pragma unroll
      for (int tn = 0; tn < 4; ++tn) {
        float s = acc[tm][tn][r];
        ls += s * (s > 0.f ? lbv[tn] : ubv[tn]);
        us += s * (s > 0.f ? ubv[tn] : lbv[tn]);
      }
#pragma unroll
      for (int off = 1; off < 16; off <<= 1) {
        ls += __shfl_xor(ls, off, 64);
        us += __shfl_xor(us, off, 64);
      }
      if (l16 == 0) {
        int i = i0 + wm + tm * 16 + quad * 4 + r;
        atomicAdd(&lb_acc[i], ls);
        atomicAdd(&ub_acc[i], us);
      }
    }
  }
}

// ---- K4: zero-fill the 134 MB output at write-BW (replaces hipMemsetAsync) ----
__global__ __launch_bounds__(256) void fill_zero(float4* __restrict__ out, int n4) {
  int idx = blockIdx.x * 256 + threadIdx.x;
  int stride = gridDim.x * 256;
  float4 z = make_float4(0.f, 0.f, 0.f, 0.f);
  for (int i = idx; i < n4; i += stride) out[i] = z;
}

// ---- K5: DeepPolyReLU elementwise + diagonal patch ----
__global__ __launch_bounds__(256) void epilogue_k(const float* __restrict__ cvec,
                                                  const float* __restrict__ lb_acc,
                                                  const float* __restrict__ ub_acc,
                                                  const float* __restrict__ raw_alpha,
                                                  float* __restrict__ out) {
  int i = blockIdx.x * 256 + threadIdx.x;
  if (i >= N) return;
  float cc = cvec[i];
  float lb = lb_acc[i] + cc;
  float ub = ub_acc[i] + cc;
  float alpha = 1.f / (1.f + expf(-raw_alpha[i]));
  float denom = ub - lb;
  float slope = (denom == 0.f) ? 0.f : ub / denom;
  bool below = ub <= 0.f, above = lb >= 0.f;
  bool crossing = !(below || above);
  float base = above ? 1.f : 0.f;
  float uslope = crossing ? slope : base;
  float uinter = crossing ? (1.f - slope) * ub : 0.f;
  float l1 = crossing ? 0.f : base;
  float l2 = crossing ? 1.f : base;
  float lslope = alpha * l1 + (1.f - alpha) * l2;
  size_t NN = (size_t)N * N;
  out[(size_t)i * N + i] = lslope;                 // diag(lslope)
  // lintercept at [NN, NN+N) stays zero from fill
  out[NN + N + (size_t)i * N + i] = uslope;        // diag(uslope)
  out[2 * NN + N + i] = uinter;                    // uintercept
}

extern "C" void kernel_launch(void* const* d_in, const int* in_sizes, int n_in,
                              void* d_out, int out_size, void* d_ws, size_t ws_size,
                              hipStream_t stream) {
  const float* raw_alpha = (const float*)d_in[0];
  const float* lb0 = (const float*)d_in[1];
  const float* ub0 = (const float*)d_in[2];
  const float* W1 = (const float*)d_in[3];
  const float* b1 = (const float*)d_in[4];
  const float* W2 = (const float*)d_in[5];
  const float* b2 = (const float*)d_in[6];

  float* cvec = (float*)d_ws;        // [N]
  float* lb_acc = cvec + N;          // [N]
  float* ub_acc = cvec + 2 * N;      // [N]

  // d_out (134 MB) doubles as bf16 scratch until the final fill
  unsigned short* W2b = (unsigned short*)d_out;       // [N*N] bf16, 32 MB
  unsigned short* W1Tb = W2b + (size_t)N * N;         // [N*N] bf16, 32 MB

  (void)hipMemsetAsync(d_ws, 0, 3 * N * sizeof(float), stream);
  convert_w2<<<N, 256, 0, stream>>>(W2, b1, b2, W2b, cvec);
  transpose_w1<<<dim3(N / 64, N / 64), 256, 0, stream>>>(W1, W1Tb);
  gemm_bounds<<<dim3(N / BN, N / BM), 256, 0, stream>>>(W2b, W1Tb, lb0, ub0, lb_acc, ub_acc);
  int n4 = out_size / 4;
  fill_zero<<<8192, 256, 0, stream>>>((float4*)d_out, n4);
  epilogue_k<<<(N + 255) / 256, 256, 0, stream>>>(cvec, lb_acc, ub_acc, raw_alpha, (float*)d_out);
}

// Round 4
// 409.581 us; speedup vs baseline: 1.0918x; 1.0056x over previous
//
#include <hip/hip_runtime.h>
#include <stdint.h>

#define N 4096
#define BM 128
#define BN 128
#define BK 64

typedef short bf16x8 __attribute__((ext_vector_type(8)));
typedef float f32x4 __attribute__((ext_vector_type(4)));

__device__ __forceinline__ unsigned short f2bf(float x) {
  union { float f; unsigned int u; } v; v.f = x;
  unsigned int u = v.u;
  unsigned int r = (u + 0x7fffu + ((u >> 16) & 1u)) >> 16;  // RNE
  return (unsigned short)r;
}

__device__ __forceinline__ void gload16(const unsigned short* g, unsigned short* l) {
  __builtin_amdgcn_global_load_lds(
      (const __attribute__((address_space(1))) unsigned int*)g,
      (__attribute__((address_space(3))) unsigned int*)l, 16, 0, 0);
}

// ---- K1: W2 fp32 -> bf16 scratch, fused c = b1 @ W2^T + b2, zero accum ----
__global__ __launch_bounds__(256) void convert_w2(const float* __restrict__ W2,
                                                  const float* __restrict__ b1,
                                                  const float* __restrict__ b2,
                                                  unsigned short* __restrict__ W2b,
                                                  float* __restrict__ c,
                                                  float* __restrict__ lb_acc,
                                                  float* __restrict__ ub_acc) {
  const int i = blockIdx.x;
  const int t = threadIdx.x;
  const float* row = W2 + (size_t)i * N;
  unsigned short* orow = W2b + (size_t)i * N;
  float dot = 0.f;
#pragma unroll
  for (int q = 0; q < 4; ++q) {
    int idx = (q * 256 + t) * 4;
    float4 w = *(const float4*)(row + idx);
    float4 b = *(const float4*)(b1 + idx);
    dot += w.x * b.x + w.y * b.y + w.z * b.z + w.w * b.w;
    ushort4 o;
    o.x = f2bf(w.x); o.y = f2bf(w.y); o.z = f2bf(w.z); o.w = f2bf(w.w);
    *(ushort4*)(orow + idx) = o;
  }
  __shared__ float red[256];
  red[t] = dot;
  __syncthreads();
  for (int s = 128; s > 0; s >>= 1) {
    if (t < s) red[t] += red[t + s];
    __syncthreads();
  }
  if (t == 0) {
    c[i] = red[0] + b2[i];
    lb_acc[i] = 0.f;   // replaces hipMemsetAsync(d_ws): gemm runs strictly after
    ub_acc[i] = 0.f;
  }
}

// ---- K2: W1 fp32 [k][j] -> bf16 W1T [j][k] (LDS tile transpose) ----
__global__ __launch_bounds__(256) void transpose_w1(const float* __restrict__ W1,
                                                    unsigned short* __restrict__ W1T) {
  __shared__ float tile[64 * 65];
  const int t = threadIdx.x;
  const int j0 = blockIdx.x * 64, k0 = blockIdx.y * 64;
#pragma unroll
  for (int s = 0; s < 4; ++s) {
    int ck = s * 256 + t;          // 0..1023
    int row = ck >> 4;             // k_local 0..63
    int col = (ck & 15) * 4;       // j_local
    float4 v = *(const float4*)(W1 + (size_t)(k0 + row) * N + j0 + col);
    float* d = &tile[row * 65 + col];
    d[0] = v.x; d[1] = v.y; d[2] = v.z; d[3] = v.w;
  }
  __syncthreads();
  int jl = t >> 2, ch = (t & 3) * 16;
  alignas(16) unsigned short outv[16];
#pragma unroll
  for (int m = 0; m < 16; ++m) outv[m] = f2bf(tile[(ch + m) * 65 + jl]);
  uint4* dst = (uint4*)(W1T + (size_t)(j0 + jl) * N + k0 + ch);
  dst[0] = *(const uint4*)&outv[0];
  dst[1] = *(const uint4*)&outv[8];
}

// ---- K3: S = W2b @ W1Tb^T (bf16 MFMA, BK=64: 32 MFMA per barrier pair),
//          fused sign-selected bound reductions ----
__global__ __launch_bounds__(256, 4) void gemm_bounds(const unsigned short* __restrict__ A,  // W2b [i][k]
                                                      const unsigned short* __restrict__ B,  // W1Tb [j][k]
                                                      const float* __restrict__ lb0,
                                                      const float* __restrict__ ub0,
                                                      float* __restrict__ lb_acc,
                                                      float* __restrict__ ub_acc) {
  __shared__ unsigned short As[BM * BK];   // 16 KB
  __shared__ unsigned short Bs[BN * BK];   // 16 KB
  const int t = threadIdx.x;
  const int lane = t & 63, w = t >> 6;
  const int wm = (w >> 1) * 64, wn = (w & 1) * 64;
  const int i0 = blockIdx.y * BM, j0 = blockIdx.x * BN;
  const int quad = lane >> 4, l16 = lane & 15;

  f32x4 acc[4][4] = {};

  // staging: thread t covers (row = t>>3 + 32*pass, 16B piece t&7)
  const unsigned short* ga = A + (size_t)(i0 + (t >> 3)) * N + (t & 7) * 8;
  const unsigned short* gb = B + (size_t)(j0 + (t >> 3)) * N + (t & 7) * 8;

  for (int kt = 0; kt < N / BK; ++kt) {
    __syncthreads();
#pragma unroll
    for (int p = 0; p < 4; ++p)
      gload16(ga + (size_t)(p * 32) * N, &As[(p * 256 + t) * 8]);
#pragma unroll
    for (int p = 0; p < 4; ++p)
      gload16(gb + (size_t)(p * 32) * N, &Bs[(p * 256 + t) * 8]);
    __syncthreads();
#pragma unroll
    for (int h = 0; h < 2; ++h) {
      bf16x8 af[4], bfr[4];
#pragma unroll
      for (int tm = 0; tm < 4; ++tm)
        af[tm] = *(const bf16x8*)&As[(wm + tm * 16 + l16) * BK + h * 32 + quad * 8];
#pragma unroll
      for (int tn = 0; tn < 4; ++tn)
        bfr[tn] = *(const bf16x8*)&Bs[(wn + tn * 16 + l16) * BK + h * 32 + quad * 8];
#pragma unroll
      for (int tm = 0; tm < 4; ++tm)
#pragma unroll
        for (int tn = 0; tn < 4; ++tn)
          acc[tm][tn] = __builtin_amdgcn_mfma_f32_16x16x32_bf16(af[tm], bfr[tn], acc[tm][tn], 0, 0, 0);
    }
    ga += BK;
    gb += BK;
  }

  // epilogue: lbounds_i += (s>0?lb0_j:ub0_j)*s ; ubounds_i += (s>0?ub0_j:lb0_j)*s
  float lbv[4], ubv[4];
#pragma unroll
  for (int tn = 0; tn < 4; ++tn) {
    int j = j0 + wn + tn * 16 + l16;
    lbv[tn] = lb0[j];
    ubv[tn] = ub0[j];
  }
#pragma unroll
  for (int tm = 0; tm < 4; ++tm) {
#pragma unroll
    for (int r = 0; r < 4; ++r) {
      float ls = 0.f, us = 0.f;
#pragma unroll
      for (int tn = 0; tn < 4; ++tn) {
        float s = acc[tm][tn][r];
        ls += s * (s > 0.f ? lbv[tn] : ubv[tn]);
        us += s * (s > 0.f ? ubv[tn] : lbv[tn]);
      }
#pragma unroll
      for (int off = 1; off < 16; off <<= 1) {
        ls += __shfl_xor(ls, off, 64);
        us += __shfl_xor(us, off, 64);
      }
      if (l16 == 0) {
        int i = i0 + wm + tm * 16 + quad * 4 + r;
        atomicAdd(&lb_acc[i], ls);
        atomicAdd(&ub_acc[i], us);
      }
    }
  }
}

// ---- K4: fused zero-fill + DeepPolyReLU patch (single pass over 134 MB) ----
struct ReluVals { float lslope, uslope, uinter; };

__device__ __forceinline__ ReluVals relu_vals(int i,
                                              const float* __restrict__ cvec,
                                              const float* __restrict__ lb_acc,
                                              const float* __restrict__ ub_acc,
                                              const float* __restrict__ raw_alpha) {
  float cc = cvec[i];
  float lb = lb_acc[i] + cc;
  float ub = ub_acc[i] + cc;
  float alpha = 1.f / (1.f + expf(-raw_alpha[i]));
  float denom = ub - lb;
  float slope = (denom == 0.f) ? 0.f : ub / denom;
  bool below = ub <= 0.f, above = lb >= 0.f;
  bool crossing = !(below || above);
  float base = above ? 1.f : 0.f;
  ReluVals v;
  v.uslope = crossing ? slope : base;
  v.uinter = crossing ? (1.f - slope) * ub : 0.f;
  float l1 = crossing ? 0.f : base;
  float l2 = crossing ? 1.f : base;
  v.lslope = alpha * l1 + (1.f - alpha) * l2;
  return v;
}

__global__ __launch_bounds__(256) void fill_patch(float4* __restrict__ out, int n4,
                                                  const float* __restrict__ cvec,
                                                  const float* __restrict__ lb_acc,
                                                  const float* __restrict__ ub_acc,
                                                  const float* __restrict__ raw_alpha) {
  const size_t NN = (size_t)N * N;
  const size_t d1_end = NN;              // diag(lslope) region
  const size_t d2_beg = NN + N;          // diag(uslope) region (after lintercept zeros)
  const size_t d2_end = 2 * NN + N;      // then uintercept tail [d2_end, d2_end+N)
  int idx = blockIdx.x * 256 + threadIdx.x;
  int stride = gridDim.x * 256;
  for (int i = idx; i < n4; i += stride) {
    size_t e = 4 * (size_t)i;
    float4 v = make_float4(0.f, 0.f, 0.f, 0.f);
    if (e >= d2_end) {                                   // uintercept tail
      int b = (int)(e - d2_end);
      v.x = relu_vals(b + 0, cvec, lb_acc, ub_acc, raw_alpha).uinter;
      v.y = relu_vals(b + 1, cvec, lb_acc, ub_acc, raw_alpha).uinter;
      v.z = relu_vals(b + 2, cvec, lb_acc, ub_acc, raw_alpha).uinter;
      v.w = relu_vals(b + 3, cvec, lb_acc, ub_acc, raw_alpha).uinter;
    } else if (e < d1_end) {                             // diag(lslope)
      int r = (int)(e >> 12), c = (int)(e & 4095);
      if (r >= c && r < c + 4)
        (&v.x)[r - c] = relu_vals(r, cvec, lb_acc, ub_acc, raw_alpha).lslope;
    } else if (e >= d2_beg) {                            // diag(uslope)
      size_t e2 = e - d2_beg;
      int r = (int)(e2 >> 12), c = (int)(e2 & 4095);
      if (r >= c && r < c + 4)
        (&v.x)[r - c] = relu_vals(r, cvec, lb_acc, ub_acc, raw_alpha).uslope;
    }
    out[i] = v;
  }
}

extern "C" void kernel_launch(void* const* d_in, const int* in_sizes, int n_in,
                              void* d_out, int out_size, void* d_ws, size_t ws_size,
                              hipStream_t stream) {
  const float* raw_alpha = (const float*)d_in[0];
  const float* lb0 = (const float*)d_in[1];
  const float* ub0 = (const float*)d_in[2];
  const float* W1 = (const float*)d_in[3];
  const float* b1 = (const float*)d_in[4];
  const float* W2 = (const float*)d_in[5];
  const float* b2 = (const float*)d_in[6];

  float* cvec = (float*)d_ws;        // [N]
  float* lb_acc = cvec + N;          // [N]
  float* ub_acc = cvec + 2 * N;      // [N]

  // d_out (134 MB) doubles as bf16 scratch until the final fill
  unsigned short* W2b = (unsigned short*)d_out;       // [N*N] bf16, 32 MB
  unsigned short* W1Tb = W2b + (size_t)N * N;         // [N*N] bf16, 32 MB

  convert_w2<<<N, 256, 0, stream>>>(W2, b1, b2, W2b, cvec, lb_acc, ub_acc);
  transpose_w1<<<dim3(N / 64, N / 64), 256, 0, stream>>>(W1, W1Tb);
  gemm_bounds<<<dim3(N / BN, N / BM), 256, 0, stream>>>(W2b, W1Tb, lb0, ub0, lb_acc, ub_acc);
  int n4 = out_size / 4;
  fill_patch<<<8192, 256, 0, stream>>>((float4*)d_out, n4, cvec, lb_acc, ub_acc, raw_alpha);
}